// Round 17
// baseline (152.647 us; speedup 1.0000x reference)
//
#include <hip/hip_runtime.h>
#include <math.h>

#define Bn 8192
#define Ee 128
#define EB 2   // batch elements per block (round-14 validated sweet spot)

typedef __attribute__((ext_vector_type(8))) short short8;   // 8 bf16 (4 VGPR) MFMA A/B frag
typedef __attribute__((ext_vector_type(4))) float f32x4;    // MFMA C/D frag

// tanh(x) = 1 - 2/(1+e^{2x}); v_exp + v_rcp, bf16-accuracy, no clamp needed.
__device__ __forceinline__ float fast_tanh(float x) {
    float e = __expf(2.f * x);
    return fmaf(-2.f, __builtin_amdgcn_rcpf(1.f + e), 1.f);
}

// round-half-up f32->bf16 (known-good from rounds 4-16)
__device__ __forceinline__ unsigned int bf1(float a) {
    return (__builtin_bit_cast(unsigned int, a) + 0x8000u) >> 16;
}
__device__ __forceinline__ unsigned int pack2bf(float a, float b) {
    unsigned int ua = (__builtin_bit_cast(unsigned int, a) + 0x8000u) >> 16;
    unsigned int ub = (__builtin_bit_cast(unsigned int, b) + 0x8000u) & 0xffff0000u;
    return ua | ub;
}
// pack two float4 (8 consecutive f32) into a bf16 short8 fragment
__device__ __forceinline__ short8 packfrag(float4 v0, float4 v1) {
    uint4 pk = {pack2bf(v0.x, v0.y), pack2bf(v0.z, v0.w),
                pack2bf(v1.x, v1.y), pack2bf(v1.z, v1.w)};
    return __builtin_bit_cast(short8, pk);
}

// ============================ MFMA main kernel: EB=2 batch elements per block ============================
// Round 17: round-14 kernel (EB=2, f32 R — the 71.8us best) with att_prep
// DELETED: A-matrix fragments are loaded straight from the f32 inputs
// (L2/L3-broadcast, 26KB) and packed to bf16 in-register — removes the
// serialized 1-block prep dispatch from the graph's critical path.
// A-frag: row=lane&15, k=(lane>>4)*8+j. B-frag: col=lane&15, k same.
// C/D: col=lane&15, row=(lane>>4)*4+reg.
__global__ __launch_bounds__(256, 4)
void att_m2(const float* __restrict__ x, const float* __restrict__ L,
            const float* __restrict__ Aq, const float* __restrict__ Ak,
            const float* __restrict__ Av, const float* __restrict__ Ao,
            float* __restrict__ R) {
    const int b0   = blockIdx.x * EB;
    const int t    = threadIdx.x;
    const int lane = t & 63;
    const int w    = t >> 6;        // wave 0..3
    const int q    = lane >> 4;     // quarter 0..3
    const int m    = lane & 15;

    __shared__ __align__(16) short sQot[EB][2560];   // sQ bf16 [32][72] U ot bf16 [64][40]
    __shared__ __align__(16) short sK[EB][2304];     // K bf16 [s][n], 144B rows
    __shared__ __align__(16) short sVt[EB][2560];    // V^T bf16 [n][s], 80B rows
    __shared__ __align__(16) short sP[EB][1280];     // exp'd scores bf16 [r][s] (unnorm.)
    __shared__ float sNum[EB];

    // ---- x column loads for BOTH b (independent streams, issued together) ----
    float xf[EB][16];
#pragma unroll
    for (int e = 0; e < EB; ++e) {
        const float* p0 = x + (size_t)(b0 + e) * 4096 + (q * 8) * 64 + (w * 16 + m);
#pragma unroll
        for (int j = 0; j < 8; ++j) xf[e][j] = p0[j * 64];
        const float* p1 = p0 + 32 * 64;
#pragma unroll
        for (int j = 0; j < 8; ++j) xf[e][8 + j] = p1[j * 64];
    }

    // ---- A-matrix fragments loaded directly from f32 (SHARED by both streams) ----
    short8 bfr[3][2][2];   // [mat][rt][k-chunk]
    {
        const float* Am[3] = {Aq, Ak, Av};
#pragma unroll
        for (int mat = 0; mat < 3; ++mat)
#pragma unroll
            for (int rt = 0; rt < 2; ++rt) {
                const float* Ab = Am[mat] + (rt * 16 + m) * 64 + q * 8;
                bfr[mat][rt][0] = packfrag(*(const float4*)Ab, *(const float4*)(Ab + 4));
                bfr[mat][rt][1] = packfrag(*(const float4*)(Ab + 32), *(const float4*)(Ab + 36));
            }
    }
    short8 aa;   // Ao frag (Rh phase): h=m, r=q*8..+7
    {
        const float* Aob = Ao + m * 32 + q * 8;
        aa = packfrag(*(const float4*)Aob, *(const float4*)(Aob + 4));
    }

    // ---- numN: wave 0 -> e=0, wave 1 -> e=1 (full-wave ballot each) ----
    if (t < 64 * EB) {
        const int e = t >> 6;
        float lv = L[(size_t)(b0 + e) * 64 + (t & 63)];
        unsigned long long mk = __ballot(lv >= 1.0f);
        if ((t & 63) == 0) sNum[e] = (float)__popcll(mk) + 1.0f;
    }

    // ---- QKV (transposed GEMM) for both streams ----
    short8 afr[EB][2];
#pragma unroll
    for (int e = 0; e < EB; ++e) {
        uint4 pk0 = {pack2bf(xf[e][0], xf[e][1]), pack2bf(xf[e][2], xf[e][3]),
                     pack2bf(xf[e][4], xf[e][5]), pack2bf(xf[e][6], xf[e][7])};
        uint4 pk1 = {pack2bf(xf[e][8], xf[e][9]), pack2bf(xf[e][10], xf[e][11]),
                     pack2bf(xf[e][12], xf[e][13]), pack2bf(xf[e][14], xf[e][15])};
        afr[e][0] = __builtin_bit_cast(short8, pk0);
        afr[e][1] = __builtin_bit_cast(short8, pk1);
    }
#pragma unroll
    for (int mat = 0; mat < 3; ++mat) {
#pragma unroll
        for (int rt = 0; rt < 2; ++rt) {
#pragma unroll
            for (int e = 0; e < EB; ++e) {
                f32x4 c = {0.f, 0.f, 0.f, 0.f};
                c = __builtin_amdgcn_mfma_f32_16x16x32_bf16(afr[e][0], bfr[mat][rt][0], c, 0, 0, 0);
                c = __builtin_amdgcn_mfma_f32_16x16x32_bf16(afr[e][1], bfr[mat][rt][1], c, 0, 0, 0);
                float tv[4];
#pragma unroll
                for (int j = 0; j < 4; ++j) tv[j] = fast_tanh(c[j]);
                if (mat < 2) {
                    // C^T write -> row-major mat[r][n]: r = rt*16+m, n0 = w*16+q*4
                    uint2 p2 = {pack2bf(tv[0], tv[1]), pack2bf(tv[2], tv[3])};
                    short* dst = (mat == 0) ? sQot[e] : sK[e];
                    *(uint2*)&dst[(rt * 16 + m) * 72 + (w * 16 + q * 4)] = p2;
                } else {
                    // V: straight write V^T[n][s]: n = w*16+q*4+j, s = rt*16+m
#pragma unroll
                    for (int j = 0; j < 4; ++j)
                        sVt[e][(w * 16 + q * 4 + j) * 40 + (rt * 16 + m)] = (short)bf1(tv[j]);
                }
            }
        }
    }
    __syncthreads();   // (1) Q/K/V staged (both streams)

    // ---- QK^T + exp for both streams: wave tile (wr, ws) ----
    // Safe without max pass: |score| <= 64 -> exp in [1.6e-28, 6.3e27].
    const int wr = w & 1, ws = w >> 1;
#pragma unroll
    for (int e = 0; e < EB; ++e) {
        short8 qa0 = *(const short8*)&sQot[e][(wr * 16 + m) * 72 + q * 8];
        short8 qa1 = *(const short8*)&sQot[e][(wr * 16 + m) * 72 + 32 + q * 8];
        short8 kb0 = *(const short8*)&sK[e][(ws * 16 + m) * 72 + q * 8];
        short8 kb1 = *(const short8*)&sK[e][(ws * 16 + m) * 72 + 32 + q * 8];
        f32x4 c = {0.f, 0.f, 0.f, 0.f};
        c = __builtin_amdgcn_mfma_f32_16x16x32_bf16(qa0, kb0, c, 0, 0, 0);
        c = __builtin_amdgcn_mfma_f32_16x16x32_bf16(qa1, kb1, c, 0, 0, 0);
        float inv = rsqrtf(sNum[e]);
#pragma unroll
        for (int j = 0; j < 4; ++j) {
            // row r = wr*16 + q*4 + j, col s = ws*16 + m
            float p = __expf(c[j] * inv);
            sP[e][(wr * 16 + q * 4 + j) * 40 + ws * 16 + m] = (short)bf1(p);
        }
    }
    __syncthreads();   // (2) sP staged (both streams)

    // ---- PV + rowsum-by-MFMA for both streams: wave w owns n-tile nt=w ----
    {
        short8 ones;
#pragma unroll
        for (int j = 0; j < 8; ++j) ones[j] = (short)0x3F80;   // bf16 1.0
#pragma unroll
        for (int e = 0; e < EB; ++e) {
            short* ot = sQot[e];  // [64][40] bf16, o^T[n][r] (sQ dead after barrier 2)
            short8 vb = *(const short8*)&sVt[e][(w * 16 + m) * 40 + q * 8];
#pragma unroll
            for (int rt = 0; rt < 2; ++rt) {
                short8 pa = *(const short8*)&sP[e][(rt * 16 + m) * 40 + q * 8];
                f32x4 z = {0.f, 0.f, 0.f, 0.f};
                f32x4 crs = __builtin_amdgcn_mfma_f32_16x16x32_bf16(pa, ones, z, 0, 0, 0);
                f32x4 cpv = __builtin_amdgcn_mfma_f32_16x16x32_bf16(pa, vb, z, 0, 0, 0);
                float ov[4];
#pragma unroll
                for (int j = 0; j < 4; ++j)
                    ov[j] = cpv[j] * __builtin_amdgcn_rcpf(crs[j]);
                // o[r=rt*16+q*4+j][n=w*16+m] -> ot[n][r]
                uint2 p2 = {pack2bf(ov[0], ov[1]), pack2bf(ov[2], ov[3])};
                *(uint2*)&ot[(w * 16 + m) * 40 + (rt * 16 + q * 4)] = p2;
            }
        }
    }
    // no barrier: Rh reads only ot rows n = w*16+m written by this wave (lgkmcnt-ordered)

    // ---- Rh + square for both streams ----
#pragma unroll
    for (int e = 0; e < EB; ++e) {
        const short* ot = sQot[e];
        short8 bb = *(const short8*)&ot[(w * 16 + m) * 40 + q * 8];
        f32x4 c = {0.f, 0.f, 0.f, 0.f};
        c = __builtin_amdgcn_mfma_f32_16x16x32_bf16(aa, bb, c, 0, 0, 0);
        float* Rb = R + (size_t)(b0 + e) * 1024;
#pragma unroll
        for (int j = 0; j < 4; ++j) {
            float rh = fast_tanh(c[j]);
            Rb[(q * 4 + j) * 64 + w * 16 + m] = rh * rh;  // h = q*4+j, n = w*16+m
        }
    }
}

// ===== Phase 2: coalesced Rsym + Laplacian (f32 R) =====
__global__ __launch_bounds__(256)
void att_k2(const float* __restrict__ R, float* __restrict__ out) {
    const int e   = blockIdx.x >> 6;
    const int rg  = blockIdx.x & 63;
    const int w   = threadIdx.x >> 6;
    const int j   = threadIdx.x & 63;
    const int row = rg * 4 + w;
    const int hr = row >> 7, i = (row >> 1) & 63, pr = row & 1;

    const float* Re = R + (size_t)e * 65536;
    float* Oe       = out + (size_t)e * 65536;

    const float* t1p = Re + i * 1024 + j * 16 + 8 * hr + 2 * pr;
    float2 t1a = *(const float2*)t1p;        // (hc=0, pc=0/1)
    float2 t1b = *(const float2*)(t1p + 4);  // (hc=1, pc=0/1)
    const float* t2p = Re + j * 1024 + i * 16 + 4 * hr + pr;
    float c00 = t1a.x + t2p[0];
    float c01 = t1a.y + t2p[2];
    float c10 = t1b.x + t2p[8];
    float c11 = t1b.y + t2p[10];

    float sum = c00 + c01 + c10 + c11;
#pragma unroll
    for (int off = 32; off >= 1; off >>= 1) sum += __shfl_xor(sum, off);

    float v00 = -c00, v01 = -c01, v10 = -c10, v11 = -c11;
    if (j == i) {
        if (hr == 0) { if (pr == 0) v00 = sum; else v01 = sum; }
        else         { if (pr == 0) v10 = sum; else v11 = sum; }
    }
    float2 z0 = {v00, v01}, z1 = {v10, v11};
    *(float2*)&Oe[row * 256 + 2 * j]       = z0;
    *(float2*)&Oe[row * 256 + 128 + 2 * j] = z1;
}

// ===== Fallback path (tiny ws): VALU kernel w/ atomic scatter + Laplacian =====
__global__ __launch_bounds__(256, 4)
void att_k1_atomic(const float* __restrict__ x, const float* __restrict__ L,
                   const float* __restrict__ Aq, const float* __restrict__ Ak,
                   const float* __restrict__ Av, const float* __restrict__ Ao,
                   float* __restrict__ out) {
    const int b    = blockIdx.x;
    const int t    = threadIdx.x;
    const int lane = t & 63;
    const int w    = t >> 6;
    const int wu   = __builtin_amdgcn_readfirstlane(w);

    __shared__ float sQ[32][68];
    __shared__ float sK[32][68];
    __shared__ float sV[32][68];
    __shared__ float sNum;

    const float* xb = x + (size_t)b * 4096;
    if (t < 64) {
        float lv = L[(size_t)b * 64 + t];
        unsigned long long mk = __ballot(lv >= 1.0f);
        if (t == 0) sNum = (float)__popcll(mk) + 1.0f;
    }
    float acc[3][8];
#pragma unroll
    for (int mm = 0; mm < 3; ++mm)
#pragma unroll
        for (int k = 0; k < 8; ++k) acc[mm][k] = 0.f;
    const float* Am[3] = {Aq, Ak, Av};
#pragma unroll
    for (int hf = 0; hf < 2; ++hf) {
        float xv[32];
#pragma unroll
        for (int d = 0; d < 32; ++d) xv[d] = xb[(hf * 32 + d) * 64 + lane];
#pragma unroll
        for (int mm = 0; mm < 3; ++mm)
#pragma unroll
            for (int k = 0; k < 8; ++k) {
                const float* Ar = Am[mm] + (wu + 4 * k) * 64 + hf * 32;
                float a = acc[mm][k];
#pragma unroll
                for (int d = 0; d < 32; ++d) a = fmaf(Ar[d], xv[d], a);
                acc[mm][k] = a;
            }
    }
    float(*const sMat[3])[68] = {sQ, sK, sV};
#pragma unroll
    for (int mm = 0; mm < 3; ++mm)
#pragma unroll
        for (int k = 0; k < 8; ++k)
            sMat[mm][wu + 4 * k][lane] = fast_tanh(acc[mm][k]);
    __syncthreads();

    const int s = lane & 31, half = lane >> 5;
    const float inv = rsqrtf(sNum);
    float kreg[32];
#pragma unroll
    for (int c = 0; c < 8; ++c) {
        float4 kv = *(const float4*)&sK[s][half * 32 + 4 * c];
        kreg[4 * c] = kv.x; kreg[4 * c + 1] = kv.y;
        kreg[4 * c + 2] = kv.z; kreg[4 * c + 3] = kv.w;
    }
    float sc8[8];
#pragma unroll
    for (int kk = 0; kk < 8; ++kk) {
        float sc = 0.f;
#pragma unroll
        for (int c = 0; c < 8; ++c) {
            float4 qv = *(const float4*)&sQ[wu + 4 * kk][half * 32 + 4 * c];
            sc = fmaf(qv.x, kreg[4 * c], sc);
            sc = fmaf(qv.y, kreg[4 * c + 1], sc);
            sc = fmaf(qv.z, kreg[4 * c + 2], sc);
            sc = fmaf(qv.w, kreg[4 * c + 3], sc);
        }
        sc += __shfl_xor(sc, 32);
        sc8[kk] = sc * inv;
    }
    float pown[4];
#pragma unroll
    for (int qq = 0; qq < 4; ++qq) pown[qq] = half ? sc8[2 * qq + 1] : sc8[2 * qq];
#pragma unroll
    for (int qq = 0; qq < 4; ++qq) {
        float e = __expf(pown[qq]);
        float ds = e;
#pragma unroll
        for (int off = 16; off >= 1; off >>= 1) ds += __shfl_xor(ds, off);
        pown[qq] = e * __builtin_amdgcn_rcpf(ds);
    }
    __syncthreads();
#pragma unroll
    for (int qq = 0; qq < 4; ++qq) sQ[wu + 8 * qq + 4 * half][s] = pown[qq];
    __syncthreads();
    float oacc[8];
#pragma unroll
    for (int k = 0; k < 8; ++k) oacc[k] = 0.f;
#pragma unroll
    for (int sb = 0; sb < 8; ++sb) {
        float4 arow[8];
#pragma unroll
        for (int kk = 0; kk < 8; ++kk) arow[kk] = *(const float4*)&sQ[wu + 4 * kk][4 * sb];
#pragma unroll
        for (int ds2 = 0; ds2 < 4; ++ds2) {
            float vv = sV[4 * sb + ds2][lane];
#pragma unroll
            for (int kk = 0; kk < 8; ++kk) {
                float a = (ds2 == 0) ? arow[kk].x : (ds2 == 1) ? arow[kk].y
                        : (ds2 == 2) ? arow[kk].z : arow[kk].w;
                oacc[kk] = fmaf(a, vv, oacc[kk]);
            }
        }
    }
#pragma unroll
    for (int k = 0; k < 8; ++k) sK[wu + 4 * k][lane] = oacc[k];
    __syncthreads();
    float col[32];
#pragma unroll
    for (int r = 0; r < 32; ++r) col[r] = sK[r][lane];
#pragma unroll
    for (int k = 0; k < 4; ++k) {
        const int h = wu + 4 * k;
        const float* AoR = Ao + h * 32;
        float a2 = 0.f;
#pragma unroll
        for (int r = 0; r < 32; ++r) a2 = fmaf(AoR[r], col[r], a2);
        float rh = fast_tanh(a2);
        float val = rh * rh;
        const int e = b >> 6, i = b & 63;
        const int c = h * 64 + lane;
        const int jj = c >> 4, k4 = c & 15;
        const int hr = (k4 >> 3) & 1, hc = (k4 >> 2) & 1;
        const int pr = (k4 >> 1) & 1, pc = k4 & 1;
        const int row = hr * 128 + 2 * i + pr;
        const int colo = hc * 128 + 2 * jj + pc;
        float* oe = out + (size_t)e * 65536;
        atomicAdd(&oe[row * 256 + colo], val);
        atomicAdd(&oe[colo * 256 + row], val);
    }
}

__global__ __launch_bounds__(256)
void att_k3(float* __restrict__ out) {
    const size_t rowbase = (size_t)blockIdx.x * 256;
    const int t = threadIdx.x;
    float v = out[rowbase + t];
    float sum = v;
#pragma unroll
    for (int off = 32; off >= 1; off >>= 1) sum += __shfl_xor(sum, off);
    __shared__ float red[4];
    if ((t & 63) == 0) red[t >> 6] = sum;
    __syncthreads();
    float tot = red[0] + red[1] + red[2] + red[3];
    const int row = blockIdx.x & 255;
    out[rowbase + t] = (t == row) ? tot : -v;
}

extern "C" void kernel_launch(void* const* d_in, const int* in_sizes, int n_in,
                              void* d_out, int out_size, void* d_ws, size_t ws_size,
                              hipStream_t stream) {
    const float* x  = (const float*)d_in[0];
    const float* L  = (const float*)d_in[1];
    const float* Aq = (const float*)d_in[2];
    const float* Ak = (const float*)d_in[3];
    const float* Av = (const float*)d_in[4];
    const float* Ao = (const float*)d_in[5];
    float* out = (float*)d_out;

    const size_t need = (size_t)Bn * 1024 * sizeof(float);
    if (ws_size >= need) {
        float* R = (float*)d_ws;
        att_m2<<<Bn / EB, 256, 0, stream>>>(x, L, Aq, Ak, Av, Ao, R);
        att_k2<<<Ee * 64, 256, 0, stream>>>(R, out);
    } else {
        (void)hipMemsetAsync(d_out, 0, (size_t)out_size * sizeof(float), stream);
        att_k1_atomic<<<Bn, 256, 0, stream>>>(x, L, Aq, Ak, Av, Ao, out);
        att_k3<<<Ee * 256, 256, 0, stream>>>(out);
    }
}

// Round 18
// 71.477 us; speedup vs baseline: 2.1356x; 2.1356x over previous
//
#include <hip/hip_runtime.h>
#include <math.h>

#define Bn 8192
#define Ee 128
#define EB 2   // batch elements per block (round-14 validated sweet spot)

typedef __attribute__((ext_vector_type(8))) short short8;   // 8 bf16 (4 VGPR) MFMA A/B frag
typedef __attribute__((ext_vector_type(4))) float f32x4;    // MFMA C/D frag

// tanh(x) = 1 - 2/(1+e^{2x}); v_exp + v_rcp, bf16-accuracy, no clamp needed.
__device__ __forceinline__ float fast_tanh(float x) {
    float e = __expf(2.f * x);
    return fmaf(-2.f, __builtin_amdgcn_rcpf(1.f + e), 1.f);
}

// round-half-up f32->bf16 (known-good from rounds 4-17)
__device__ __forceinline__ unsigned int bf1(float a) {
    return (__builtin_bit_cast(unsigned int, a) + 0x8000u) >> 16;
}
__device__ __forceinline__ unsigned int pack2bf(float a, float b) {
    unsigned int ua = (__builtin_bit_cast(unsigned int, a) + 0x8000u) >> 16;
    unsigned int ub = (__builtin_bit_cast(unsigned int, b) + 0x8000u) & 0xffff0000u;
    return ua | ub;
}

// ---- prep: one-shot f32->bf16 conversion of Aq/Ak/Av (3x[32][64]) + Ao ([16][32])
// Load-bearing (round-17 lesson): keeps m2's A-fragment loads at one dwordx4
// each and the register file under budget — fusing it into m2 causes spill.
__global__ __launch_bounds__(256)
void att_prep(const float* __restrict__ Aq, const float* __restrict__ Ak,
              const float* __restrict__ Av, const float* __restrict__ Ao,
              short* __restrict__ Abf) {
    const int t = threadIdx.x;
    const float* Am[3] = {Aq, Ak, Av};
#pragma unroll
    for (int mat = 0; mat < 3; ++mat) {
        float4 v0 = *(const float4*)(Am[mat] + t * 8);
        float4 v1 = *(const float4*)(Am[mat] + t * 8 + 4);
        uint4 pk = {pack2bf(v0.x, v0.y), pack2bf(v0.z, v0.w),
                    pack2bf(v1.x, v1.y), pack2bf(v1.z, v1.w)};
        *(uint4*)&Abf[mat * 2048 + t * 8] = pk;
    }
    if (t < 64) {
        float4 v0 = *(const float4*)(Ao + t * 8);
        float4 v1 = *(const float4*)(Ao + t * 8 + 4);
        uint4 pk = {pack2bf(v0.x, v0.y), pack2bf(v0.z, v0.w),
                    pack2bf(v1.x, v1.y), pack2bf(v1.z, v1.w)};
        *(uint4*)&Abf[6144 + t * 8] = pk;
    }
}

// ============================ MFMA main kernel: EB=2 batch elements per block ============================
// Round 18: exact restore of the round-14 session best (71.8us).
// A-frag: row=lane&15, k=(lane>>4)*8+j. B-frag: col=lane&15, k same.
// C/D: col=lane&15, row=(lane>>4)*4+reg.
__global__ __launch_bounds__(256, 4)
void att_m2(const float* __restrict__ x, const float* __restrict__ L,
            const short* __restrict__ Abf, float* __restrict__ R) {
    const int b0   = blockIdx.x * EB;
    const int t    = threadIdx.x;
    const int lane = t & 63;
    const int w    = t >> 6;        // wave 0..3
    const int q    = lane >> 4;     // quarter 0..3
    const int m    = lane & 15;

    __shared__ __align__(16) short sQot[EB][2560];   // sQ bf16 [32][72] U ot bf16 [64][40]
    __shared__ __align__(16) short sK[EB][2304];     // K bf16 [s][n], 144B rows
    __shared__ __align__(16) short sVt[EB][2560];    // V^T bf16 [n][s], 80B rows
    __shared__ __align__(16) short sP[EB][1280];     // exp'd scores bf16 [r][s] (unnorm.)
    __shared__ float sNum[EB];

    // ---- x column loads for BOTH b (independent streams, issued together) ----
    float xf[EB][16];
#pragma unroll
    for (int e = 0; e < EB; ++e) {
        const float* p0 = x + (size_t)(b0 + e) * 4096 + (q * 8) * 64 + (w * 16 + m);
#pragma unroll
        for (int j = 0; j < 8; ++j) xf[e][j] = p0[j * 64];
        const float* p1 = p0 + 32 * 64;
#pragma unroll
        for (int j = 0; j < 8; ++j) xf[e][8 + j] = p1[j * 64];
    }

    // ---- A-matrix fragments (SHARED by both streams) ----
    short8 bfr[3][2][2];   // [mat][rt][k-chunk]
#pragma unroll
    for (int mat = 0; mat < 3; ++mat)
#pragma unroll
        for (int rt = 0; rt < 2; ++rt) {
            const short* Ab = Abf + mat * 2048 + (rt * 16 + m) * 64 + q * 8;
            bfr[mat][rt][0] = *(const short8*)Ab;
            bfr[mat][rt][1] = *(const short8*)(Ab + 32);
        }
    short8 aa = *(const short8*)&Abf[6144 + m * 32 + q * 8];   // Ao frag

    // ---- numN: wave 0 -> e=0, wave 1 -> e=1 (full-wave ballot each) ----
    if (t < 64 * EB) {
        const int e = t >> 6;
        float lv = L[(size_t)(b0 + e) * 64 + (t & 63)];
        unsigned long long mk = __ballot(lv >= 1.0f);
        if ((t & 63) == 0) sNum[e] = (float)__popcll(mk) + 1.0f;
    }

    // ---- QKV (transposed GEMM) for both streams ----
    short8 afr[EB][2];
#pragma unroll
    for (int e = 0; e < EB; ++e) {
        uint4 pk0 = {pack2bf(xf[e][0], xf[e][1]), pack2bf(xf[e][2], xf[e][3]),
                     pack2bf(xf[e][4], xf[e][5]), pack2bf(xf[e][6], xf[e][7])};
        uint4 pk1 = {pack2bf(xf[e][8], xf[e][9]), pack2bf(xf[e][10], xf[e][11]),
                     pack2bf(xf[e][12], xf[e][13]), pack2bf(xf[e][14], xf[e][15])};
        afr[e][0] = __builtin_bit_cast(short8, pk0);
        afr[e][1] = __builtin_bit_cast(short8, pk1);
    }
#pragma unroll
    for (int mat = 0; mat < 3; ++mat) {
#pragma unroll
        for (int rt = 0; rt < 2; ++rt) {
#pragma unroll
            for (int e = 0; e < EB; ++e) {
                f32x4 c = {0.f, 0.f, 0.f, 0.f};
                c = __builtin_amdgcn_mfma_f32_16x16x32_bf16(afr[e][0], bfr[mat][rt][0], c, 0, 0, 0);
                c = __builtin_amdgcn_mfma_f32_16x16x32_bf16(afr[e][1], bfr[mat][rt][1], c, 0, 0, 0);
                float tv[4];
#pragma unroll
                for (int j = 0; j < 4; ++j) tv[j] = fast_tanh(c[j]);
                if (mat < 2) {
                    // C^T write -> row-major mat[r][n]: r = rt*16+m, n0 = w*16+q*4
                    uint2 p2 = {pack2bf(tv[0], tv[1]), pack2bf(tv[2], tv[3])};
                    short* dst = (mat == 0) ? sQot[e] : sK[e];
                    *(uint2*)&dst[(rt * 16 + m) * 72 + (w * 16 + q * 4)] = p2;
                } else {
                    // V: straight write V^T[n][s]: n = w*16+q*4+j, s = rt*16+m
#pragma unroll
                    for (int j = 0; j < 4; ++j)
                        sVt[e][(w * 16 + q * 4 + j) * 40 + (rt * 16 + m)] = (short)bf1(tv[j]);
                }
            }
        }
    }
    __syncthreads();   // (1) Q/K/V staged (both streams)

    // ---- QK^T + exp for both streams: wave tile (wr, ws) ----
    // Safe without max pass: |score| <= 64 -> exp in [1.6e-28, 6.3e27].
    const int wr = w & 1, ws = w >> 1;
#pragma unroll
    for (int e = 0; e < EB; ++e) {
        short8 qa0 = *(const short8*)&sQot[e][(wr * 16 + m) * 72 + q * 8];
        short8 qa1 = *(const short8*)&sQot[e][(wr * 16 + m) * 72 + 32 + q * 8];
        short8 kb0 = *(const short8*)&sK[e][(ws * 16 + m) * 72 + q * 8];
        short8 kb1 = *(const short8*)&sK[e][(ws * 16 + m) * 72 + 32 + q * 8];
        f32x4 c = {0.f, 0.f, 0.f, 0.f};
        c = __builtin_amdgcn_mfma_f32_16x16x32_bf16(qa0, kb0, c, 0, 0, 0);
        c = __builtin_amdgcn_mfma_f32_16x16x32_bf16(qa1, kb1, c, 0, 0, 0);
        float inv = rsqrtf(sNum[e]);
#pragma unroll
        for (int j = 0; j < 4; ++j) {
            // row r = wr*16 + q*4 + j, col s = ws*16 + m
            float p = __expf(c[j] * inv);
            sP[e][(wr * 16 + q * 4 + j) * 40 + ws * 16 + m] = (short)bf1(p);
        }
    }
    __syncthreads();   // (2) sP staged (both streams)

    // ---- PV + rowsum-by-MFMA for both streams: wave w owns n-tile nt=w ----
    {
        short8 ones;
#pragma unroll
        for (int j = 0; j < 8; ++j) ones[j] = (short)0x3F80;   // bf16 1.0
#pragma unroll
        for (int e = 0; e < EB; ++e) {
            short* ot = sQot[e];  // [64][40] bf16, o^T[n][r] (sQ dead after barrier 2)
            short8 vb = *(const short8*)&sVt[e][(w * 16 + m) * 40 + q * 8];
#pragma unroll
            for (int rt = 0; rt < 2; ++rt) {
                short8 pa = *(const short8*)&sP[e][(rt * 16 + m) * 40 + q * 8];
                f32x4 z = {0.f, 0.f, 0.f, 0.f};
                f32x4 crs = __builtin_amdgcn_mfma_f32_16x16x32_bf16(pa, ones, z, 0, 0, 0);
                f32x4 cpv = __builtin_amdgcn_mfma_f32_16x16x32_bf16(pa, vb, z, 0, 0, 0);
                float ov[4];
#pragma unroll
                for (int j = 0; j < 4; ++j)
                    ov[j] = cpv[j] * __builtin_amdgcn_rcpf(crs[j]);
                // o[r=rt*16+q*4+j][n=w*16+m] -> ot[n][r]
                uint2 p2 = {pack2bf(ov[0], ov[1]), pack2bf(ov[2], ov[3])};
                *(uint2*)&ot[(w * 16 + m) * 40 + (rt * 16 + q * 4)] = p2;
            }
        }
    }
    // no barrier: Rh reads only ot rows n = w*16+m written by this wave (lgkmcnt-ordered)

    // ---- Rh + square for both streams ----
#pragma unroll
    for (int e = 0; e < EB; ++e) {
        const short* ot = sQot[e];
        short8 bb = *(const short8*)&ot[(w * 16 + m) * 40 + q * 8];
        f32x4 c = {0.f, 0.f, 0.f, 0.f};
        c = __builtin_amdgcn_mfma_f32_16x16x32_bf16(aa, bb, c, 0, 0, 0);
        float* Rb = R + (size_t)(b0 + e) * 1024;
#pragma unroll
        for (int j = 0; j < 4; ++j) {
            float rh = fast_tanh(c[j]);
            Rb[(q * 4 + j) * 64 + w * 16 + m] = rh * rh;  // h = q*4+j, n = w*16+m
        }
    }
}

// ===== Phase 2: coalesced Rsym + Laplacian =====
__global__ __launch_bounds__(256)
void att_k2(const float* __restrict__ R, float* __restrict__ out) {
    const int e   = blockIdx.x >> 6;
    const int rg  = blockIdx.x & 63;
    const int w   = threadIdx.x >> 6;
    const int j   = threadIdx.x & 63;
    const int row = rg * 4 + w;
    const int hr = row >> 7, i = (row >> 1) & 63, pr = row & 1;

    const float* Re = R + (size_t)e * 65536;
    float* Oe       = out + (size_t)e * 65536;

    const float* t1p = Re + i * 1024 + j * 16 + 8 * hr + 2 * pr;
    float2 t1a = *(const float2*)t1p;        // (hc=0, pc=0/1)
    float2 t1b = *(const float2*)(t1p + 4);  // (hc=1, pc=0/1)
    const float* t2p = Re + j * 1024 + i * 16 + 4 * hr + pr;
    float c00 = t1a.x + t2p[0];
    float c01 = t1a.y + t2p[2];
    float c10 = t1b.x + t2p[8];
    float c11 = t1b.y + t2p[10];

    float sum = c00 + c01 + c10 + c11;
#pragma unroll
    for (int off = 32; off >= 1; off >>= 1) sum += __shfl_xor(sum, off);

    float v00 = -c00, v01 = -c01, v10 = -c10, v11 = -c11;
    if (j == i) {
        if (hr == 0) { if (pr == 0) v00 = sum; else v01 = sum; }
        else         { if (pr == 0) v10 = sum; else v11 = sum; }
    }
    float2 z0 = {v00, v01}, z1 = {v10, v11};
    *(float2*)&Oe[row * 256 + 2 * j]       = z0;
    *(float2*)&Oe[row * 256 + 128 + 2 * j] = z1;
}

// ===== Fallback path (tiny ws): VALU kernel w/ atomic scatter + Laplacian =====
__global__ __launch_bounds__(256, 4)
void att_k1_atomic(const float* __restrict__ x, const float* __restrict__ L,
                   const float* __restrict__ Aq, const float* __restrict__ Ak,
                   const float* __restrict__ Av, const float* __restrict__ Ao,
                   float* __restrict__ out) {
    const int b    = blockIdx.x;
    const int t    = threadIdx.x;
    const int lane = t & 63;
    const int w    = t >> 6;
    const int wu   = __builtin_amdgcn_readfirstlane(w);

    __shared__ float sQ[32][68];
    __shared__ float sK[32][68];
    __shared__ float sV[32][68];
    __shared__ float sNum;

    const float* xb = x + (size_t)b * 4096;
    if (t < 64) {
        float lv = L[(size_t)b * 64 + t];
        unsigned long long mk = __ballot(lv >= 1.0f);
        if (t == 0) sNum = (float)__popcll(mk) + 1.0f;
    }
    float acc[3][8];
#pragma unroll
    for (int mm = 0; mm < 3; ++mm)
#pragma unroll
        for (int k = 0; k < 8; ++k) acc[mm][k] = 0.f;
    const float* Am[3] = {Aq, Ak, Av};
#pragma unroll
    for (int hf = 0; hf < 2; ++hf) {
        float xv[32];
#pragma unroll
        for (int d = 0; d < 32; ++d) xv[d] = xb[(hf * 32 + d) * 64 + lane];
#pragma unroll
        for (int mm = 0; mm < 3; ++mm)
#pragma unroll
            for (int k = 0; k < 8; ++k) {
                const float* Ar = Am[mm] + (wu + 4 * k) * 64 + hf * 32;
                float a = acc[mm][k];
#pragma unroll
                for (int d = 0; d < 32; ++d) a = fmaf(Ar[d], xv[d], a);
                acc[mm][k] = a;
            }
    }
    float(*const sMat[3])[68] = {sQ, sK, sV};
#pragma unroll
    for (int mm = 0; mm < 3; ++mm)
#pragma unroll
        for (int k = 0; k < 8; ++k)
            sMat[mm][wu + 4 * k][lane] = fast_tanh(acc[mm][k]);
    __syncthreads();

    const int s = lane & 31, half = lane >> 5;
    const float inv = rsqrtf(sNum);
    float kreg[32];
#pragma unroll
    for (int c = 0; c < 8; ++c) {
        float4 kv = *(const float4*)&sK[s][half * 32 + 4 * c];
        kreg[4 * c] = kv.x; kreg[4 * c + 1] = kv.y;
        kreg[4 * c + 2] = kv.z; kreg[4 * c + 3] = kv.w;
    }
    float sc8[8];
#pragma unroll
    for (int kk = 0; kk < 8; ++kk) {
        float sc = 0.f;
#pragma unroll
        for (int c = 0; c < 8; ++c) {
            float4 qv = *(const float4*)&sQ[wu + 4 * kk][half * 32 + 4 * c];
            sc = fmaf(qv.x, kreg[4 * c], sc);
            sc = fmaf(qv.y, kreg[4 * c + 1], sc);
            sc = fmaf(qv.z, kreg[4 * c + 2], sc);
            sc = fmaf(qv.w, kreg[4 * c + 3], sc);
        }
        sc += __shfl_xor(sc, 32);
        sc8[kk] = sc * inv;
    }
    float pown[4];
#pragma unroll
    for (int qq = 0; qq < 4; ++qq) pown[qq] = half ? sc8[2 * qq + 1] : sc8[2 * qq];
#pragma unroll
    for (int qq = 0; qq < 4; ++qq) {
        float e = __expf(pown[qq]);
        float ds = e;
#pragma unroll
        for (int off = 16; off >= 1; off >>= 1) ds += __shfl_xor(ds, off);
        pown[qq] = e * __builtin_amdgcn_rcpf(ds);
    }
    __syncthreads();
#pragma unroll
    for (int qq = 0; qq < 4; ++qq) sQ[wu + 8 * qq + 4 * half][s] = pown[qq];
    __syncthreads();
    float oacc[8];
#pragma unroll
    for (int k = 0; k < 8; ++k) oacc[k] = 0.f;
#pragma unroll
    for (int sb = 0; sb < 8; ++sb) {
        float4 arow[8];
#pragma unroll
        for (int kk = 0; kk < 8; ++kk) arow[kk] = *(const float4*)&sQ[wu + 4 * kk][4 * sb];
#pragma unroll
        for (int ds2 = 0; ds2 < 4; ++ds2) {
            float vv = sV[4 * sb + ds2][lane];
#pragma unroll
            for (int kk = 0; kk < 8; ++kk) {
                float a = (ds2 == 0) ? arow[kk].x : (ds2 == 1) ? arow[kk].y
                        : (ds2 == 2) ? arow[kk].z : arow[kk].w;
                oacc[kk] = fmaf(a, vv, oacc[kk]);
            }
        }
    }
#pragma unroll
    for (int k = 0; k < 8; ++k) sK[wu + 4 * k][lane] = oacc[k];
    __syncthreads();
    float col[32];
#pragma unroll
    for (int r = 0; r < 32; ++r) col[r] = sK[r][lane];
#pragma unroll
    for (int k = 0; k < 4; ++k) {
        const int h = wu + 4 * k;
        const float* AoR = Ao + h * 32;
        float a2 = 0.f;
#pragma unroll
        for (int r = 0; r < 32; ++r) a2 = fmaf(AoR[r], col[r], a2);
        float rh = fast_tanh(a2);
        float val = rh * rh;
        const int e = b >> 6, i = b & 63;
        const int c = h * 64 + lane;
        const int jj = c >> 4, k4 = c & 15;
        const int hr = (k4 >> 3) & 1, hc = (k4 >> 2) & 1;
        const int pr = (k4 >> 1) & 1, pc = k4 & 1;
        const int row = hr * 128 + 2 * i + pr;
        const int colo = hc * 128 + 2 * jj + pc;
        float* oe = out + (size_t)e * 65536;
        atomicAdd(&oe[row * 256 + colo], val);
        atomicAdd(&oe[colo * 256 + row], val);
    }
}

__global__ __launch_bounds__(256)
void att_k3(float* __restrict__ out) {
    const size_t rowbase = (size_t)blockIdx.x * 256;
    const int t = threadIdx.x;
    float v = out[rowbase + t];
    float sum = v;
#pragma unroll
    for (int off = 32; off >= 1; off >>= 1) sum += __shfl_xor(sum, off);
    __shared__ float red[4];
    if ((t & 63) == 0) red[t >> 6] = sum;
    __syncthreads();
    float tot = red[0] + red[1] + red[2] + red[3];
    const int row = blockIdx.x & 255;
    out[rowbase + t] = (t == row) ? tot : -v;
}

extern "C" void kernel_launch(void* const* d_in, const int* in_sizes, int n_in,
                              void* d_out, int out_size, void* d_ws, size_t ws_size,
                              hipStream_t stream) {
    const float* x  = (const float*)d_in[0];
    const float* L  = (const float*)d_in[1];
    const float* Aq = (const float*)d_in[2];
    const float* Ak = (const float*)d_in[3];
    const float* Av = (const float*)d_in[4];
    const float* Ao = (const float*)d_in[5];
    float* out = (float*)d_out;

    const size_t rbytes = (size_t)Bn * 1024 * sizeof(float);
    const size_t need   = rbytes + 6656 * sizeof(short);
    if (ws_size >= need) {
        float* R   = (float*)d_ws;
        short* Abf = (short*)((char*)d_ws + rbytes);
        att_prep<<<1, 256, 0, stream>>>(Aq, Ak, Av, Ao, Abf);
        att_m2<<<Bn / EB, 256, 0, stream>>>(x, L, Abf, R);
        att_k2<<<Ee * 64, 256, 0, stream>>>(R, out);
    } else {
        (void)hipMemsetAsync(d_out, 0, (size_t)out_size * sizeof(float), stream);
        att_k1_atomic<<<Bn, 256, 0, stream>>>(x, L, Aq, Ak, Av, Ao, out);
        att_k3<<<Ee * 256, 256, 0, stream>>>(out);
    }
}